// Round 7
// baseline (3389.702 us; speedup 1.0000x reference)
//
#include <hip/hip_runtime.h>
#include <hip/hip_bf16.h>
#include <math.h>

#define N_NODES 50000
#define N_EDGES 1600000
#define NFEAT 512
#define NHID 128
#define NCLASS 40

#define NBUCKETS 196      // ceil(N_NODES / 256), dst>>8
#define BUCKET_CAP 16384  // avg fill ~8163
#define NSUB 784          // NBUCKETS*4 sub-buckets of 64 dst (782 used)
#define SUBCAP 4096       // avg fill ~2041

typedef __attribute__((ext_vector_type(8))) short bf16x8;
typedef __attribute__((ext_vector_type(4))) float f32x4;

static __device__ __forceinline__ float asfloat_u32(unsigned int u) {
    union { unsigned int u; float f; } c;
    c.u = u;
    return c.f;
}
static __device__ __forceinline__ unsigned int asu32_f(float f) {
    union { float f; unsigned int u; } c;
    c.f = f;
    return c.u;
}
static __device__ __forceinline__ unsigned short f2bf(float f) {
    union { float f; unsigned int u; } c;
    c.f = f;
    unsigned int r = c.u + 0x7FFFu + ((c.u >> 16) & 1u);  // RTN-even
    return (unsigned short)(r >> 16);
}

// ---------------- prep: bucket cursor init + both weight transposes ----------------
__global__ __launch_bounds__(256) void prep_kernel(const float* __restrict__ W1,
                                                   unsigned short* __restrict__ Wt1,
                                                   const float* __restrict__ Wh,
                                                   unsigned short* __restrict__ Wth,
                                                   int* __restrict__ bucketCursor) {
    int idx = blockIdx.x * 256 + threadIdx.x;
    if (idx < NFEAT * NHID) {  // Wt1[n][k] = bf16(W1[k][n])
        int k = idx >> 7;      // /NHID
        int n = idx & 127;
        Wt1[(size_t)n * NFEAT + k] = f2bf(W1[idx]);
    } else if (idx < NFEAT * NHID + NHID * NHID) {
        int j = idx - NFEAT * NHID;
        int k = j >> 7;
        int n = j & 127;
        Wth[(size_t)n * NHID + k] = f2bf(Wh[j]);
    } else {
        int j = idx - (NFEAT * NHID + NHID * NHID);
        if (j < NBUCKETS) bucketCursor[j] = j * BUCKET_CAP;
    }
}

// ---------------- Pass 1: bin by dst>>8 ----------------
// Record: x = src | (dstLow8)<<16 ; y = fp32 weight bits.
__global__ __launch_bounds__(256) void bin_kernel(const int* __restrict__ src,
                                                  const int* __restrict__ dst,
                                                  const float* __restrict__ w,
                                                  int* __restrict__ bucketCursor,
                                                  uint2* __restrict__ binned, int n) {
    __shared__ int hist[NBUCKETS];
    __shared__ int cur[NBUCKETS];
    const int tid = threadIdx.x;
    const int base = blockIdx.x * 4096;
    if (tid < NBUCKETS) hist[tid] = 0;
    __syncthreads();
#pragma unroll
    for (int r = 0; r < 16; ++r) {
        int e = base + r * 256 + tid;
        if (e < n) atomicAdd(&hist[dst[e] >> 8], 1);
    }
    __syncthreads();
    if (tid < NBUCKETS && hist[tid] > 0)
        cur[tid] = atomicAdd(&bucketCursor[tid], hist[tid]);
    __syncthreads();
#pragma unroll
    for (int r = 0; r < 16; ++r) {
        int e = base + r * 256 + tid;
        if (e < n) {
            int d = dst[e];
            int pos = atomicAdd(&cur[d >> 8], 1);
            uint2 rec;
            rec.x = (unsigned int)src[e] | ((unsigned int)(d & 255) << 16);
            rec.y = asu32_f(w[e]);
            binned[pos] = rec;
        }
    }
}

// ---------------- Pass 2: per-bucket counting sort -> 4 sub-buckets (64 dst),
//                  each sorted by src>>8; fixed-capacity SUBCAP regions ----------------
// Out record: x = src | (dstLow6)<<16 ; y = fp32 weight bits. subCnt[4b+j] = fill.
__global__ __launch_bounds__(256) void sort_kernel(const uint2* __restrict__ binned,
                                                   const int* __restrict__ bucketCursor,
                                                   uint2* __restrict__ binned2,
                                                   int* __restrict__ subCnt) {
    __shared__ int hist[1024];     // 784 used (key = j*196 + srcbin), zero-padded
    __shared__ int partial[256];
    __shared__ int subStart[4];
    const int b = blockIdx.x;
    const int tid = threadIdx.x;
    const int cnt = bucketCursor[b] - b * BUCKET_CAP;
    const uint2* seg = binned + (size_t)b * BUCKET_CAP;

#pragma unroll
    for (int k = 0; k < 4; ++k) hist[tid * 4 + k] = 0;
    __syncthreads();
    for (int i = tid; i < cnt; i += 256) {
        unsigned int x = seg[i].x;
        int key = (int)(((x >> 22) & 3u) * 196u + ((x & 0xFFFFu) >> 8));
        atomicAdd(&hist[key], 1);
    }
    __syncthreads();
    // exclusive scan over 1024 bins (784 meaningful)
    int s0 = hist[tid * 4], s1 = hist[tid * 4 + 1], s2 = hist[tid * 4 + 2], s3 = hist[tid * 4 + 3];
    int mySum = s0 + s1 + s2 + s3;
    partial[tid] = mySum;
    __syncthreads();
    for (int off = 1; off < 256; off <<= 1) {
        int t = (tid >= off) ? partial[tid - off] : 0;
        __syncthreads();
        partial[tid] += t;
        __syncthreads();
    }
    int base = partial[tid] - mySum;
    hist[tid * 4] = base;
    hist[tid * 4 + 1] = base + s0;
    hist[tid * 4 + 2] = base + s0 + s1;
    hist[tid * 4 + 3] = base + s0 + s1 + s2;
    __syncthreads();
    if (tid < 4) {
        int st = hist[tid * 196];
        int en = (tid < 3) ? hist[(tid + 1) * 196] : cnt;
        subStart[tid] = st;
        subCnt[b * 4 + tid] = en - st;
    }
    __syncthreads();
    for (int i = tid; i < cnt; i += 256) {
        uint2 p = seg[i];
        unsigned int x = p.x;
        int j = (int)((x >> 22) & 3u);
        int key = j * 196 + (int)((x & 0xFFFFu) >> 8);
        int pos = atomicAdd(&hist[key], 1);  // absolute position within bucket
        uint2 rec;
        rec.x = (x & 0xFFFFu) | (((x >> 16) & 63u) << 16);
        rec.y = p.y;
        binned2[(size_t)(b * 4 + j) * SUBCAP + (pos - subStart[j])] = rec;
    }
}

// ---------------- LDS-tiled MFMA GEMM, N=128 ----------------
#define LDP 40
template <bool A_IS_BF16>
__global__ __launch_bounds__(256) void gemm_tile_n128(const void* __restrict__ Ap,
                                                      const unsigned short* __restrict__ Wt,
                                                      unsigned short* __restrict__ C,
                                                      const int M, const int K) {
    __shared__ unsigned short As[128 * LDP];
    __shared__ unsigned short Bs[128 * LDP];
    const int tid = threadIdx.x;
    const int wave = tid >> 6;
    const int lane = tid & 63;
    const int ln = lane & 15;
    const int quad = lane >> 4;
    const int row0 = blockIdx.x * 128;

    const int sr = tid >> 1;
    const int half = tid & 1;
    const bool srOk = (row0 + sr) < M;

    f32x4 acc0[8], acc1[8];
#pragma unroll
    for (int t = 0; t < 8; ++t) {
        acc0[t] = (f32x4){0.f, 0.f, 0.f, 0.f};
        acc1[t] = (f32x4){0.f, 0.f, 0.f, 0.f};
    }

    const int wrow = wave * 32;

    for (int kc = 0; kc < K; kc += 32) {
        bf16x8 va0, va1;
        if (A_IS_BF16) {
            if (srOk) {
                const unsigned short* Ab =
                    (const unsigned short*)Ap + (size_t)(row0 + sr) * K + kc + half * 16;
                va0 = *(const bf16x8*)Ab;
                va1 = *(const bf16x8*)(Ab + 8);
            } else {
#pragma unroll
                for (int i = 0; i < 8; ++i) { va0[i] = 0; va1[i] = 0; }
            }
        } else {
            if (srOk) {
                const float* Af = (const float*)Ap + (size_t)(row0 + sr) * K + kc + half * 16;
                float4 f0 = *(const float4*)(Af);
                float4 f1 = *(const float4*)(Af + 4);
                float4 f2 = *(const float4*)(Af + 8);
                float4 f3 = *(const float4*)(Af + 12);
                va0[0] = (short)f2bf(f0.x); va0[1] = (short)f2bf(f0.y);
                va0[2] = (short)f2bf(f0.z); va0[3] = (short)f2bf(f0.w);
                va0[4] = (short)f2bf(f1.x); va0[5] = (short)f2bf(f1.y);
                va0[6] = (short)f2bf(f1.z); va0[7] = (short)f2bf(f1.w);
                va1[0] = (short)f2bf(f2.x); va1[1] = (short)f2bf(f2.y);
                va1[2] = (short)f2bf(f2.z); va1[3] = (short)f2bf(f2.w);
                va1[4] = (short)f2bf(f3.x); va1[5] = (short)f2bf(f3.y);
                va1[6] = (short)f2bf(f3.z); va1[7] = (short)f2bf(f3.w);
            } else {
#pragma unroll
                for (int i = 0; i < 8; ++i) { va0[i] = 0; va1[i] = 0; }
            }
        }
        const unsigned short* Bg = Wt + (size_t)sr * K + kc + half * 16;
        bf16x8 vb0 = *(const bf16x8*)Bg;
        bf16x8 vb1 = *(const bf16x8*)(Bg + 8);

        *(bf16x8*)&As[sr * LDP + half * 16] = va0;
        *(bf16x8*)&As[sr * LDP + half * 16 + 8] = va1;
        *(bf16x8*)&Bs[sr * LDP + half * 16] = vb0;
        *(bf16x8*)&Bs[sr * LDP + half * 16 + 8] = vb1;
        __syncthreads();

        bf16x8 a0 = *(const bf16x8*)&As[(wrow + ln) * LDP + quad * 8];
        bf16x8 a1 = *(const bf16x8*)&As[(wrow + 16 + ln) * LDP + quad * 8];
#pragma unroll
        for (int t = 0; t < 8; ++t) {
            bf16x8 b = *(const bf16x8*)&Bs[(t * 16 + ln) * LDP + quad * 8];
            acc0[t] = __builtin_amdgcn_mfma_f32_16x16x32_bf16(a0, b, acc0[t], 0, 0, 0);
            acc1[t] = __builtin_amdgcn_mfma_f32_16x16x32_bf16(a1, b, acc1[t], 0, 0, 0);
        }
        __syncthreads();
    }

#pragma unroll
    for (int t = 0; t < 8; ++t) {
#pragma unroll
        for (int r = 0; r < 4; ++r) {
            int row = row0 + wrow + quad * 4 + r;
            if (row < M) C[(size_t)row * 128 + t * 16 + ln] = f2bf(acc0[t][r]);
            row += 16;
            if (row < M) C[(size_t)row * 128 + t * 16 + ln] = f2bf(acc1[t][r]);
        }
    }
}

// ---------------- GEMM, N=40, K=128, A bf16 -> C bf16 ----------------
__global__ __launch_bounds__(256) void gemm_n40_bf16A(const unsigned short* __restrict__ A,
                                                      const float* __restrict__ Bm,
                                                      unsigned short* __restrict__ C, int M) {
    __shared__ float As[64][132];
    __shared__ float Bs[128 * 40];
    const int tid = threadIdx.x;
    const int tr = tid >> 2;
    const int tc = tid & 3;
    const int row0 = blockIdx.x * 64;

#pragma unroll
    for (int q = tid; q < 2048; q += 256) {
        int r = q >> 5;
        int c = (q & 31) << 2;
        int row = row0 + r;
        uint2 u = make_uint2(0u, 0u);
        if (row < M) u = *(const uint2*)(A + (size_t)row * 128 + c);
        As[r][c + 0] = asfloat_u32(u.x << 16);
        As[r][c + 1] = asfloat_u32(u.x & 0xFFFF0000u);
        As[r][c + 2] = asfloat_u32(u.y << 16);
        As[r][c + 3] = asfloat_u32(u.y & 0xFFFF0000u);
    }
    for (int q = tid; q < 128 * 40; q += 256) Bs[q] = Bm[q];
    __syncthreads();

    float acc[10];
#pragma unroll
    for (int j = 0; j < 10; ++j) acc[j] = 0.f;

    for (int k = 0; k < 128; ++k) {
        float a = As[tr][k];
#pragma unroll
        for (int j = 0; j < 10; ++j) acc[j] += a * Bs[k * 40 + tc * 10 + j];
    }

    int row = row0 + tr;
    if (row < M) {
#pragma unroll
        for (int j = 0; j < 10; ++j) C[(size_t)row * 40 + tc * 10 + j] = f2bf(acc[j]);
    }
}

// ---------------- SpMM via per-sub-bucket LDS accumulator + bias + ReLU ----------------
// One block per 64-dst sub-bucket; edges sorted by src>>8 -> L2-local gather.
__global__ __launch_bounds__(256) void spmm_lds_relu(const unsigned short* __restrict__ t,
                                                     const uint2* __restrict__ binned2,
                                                     const int* __restrict__ subCnt,
                                                     const float* __restrict__ bias,
                                                     unsigned short* __restrict__ out) {
    __shared__ float acc[64 * 128];  // 32 KB
    const int b = blockIdx.x;
    const int tid = threadIdx.x;
    const int wave = tid >> 6;
    const int lane = tid & 63;
    const int cnt = subCnt[b];
    const uint2* seg = binned2 + (size_t)b * SUBCAP;

    for (int i = tid; i < 64 * 128; i += 256) acc[i] = 0.f;
    __syncthreads();

    int e = wave;
    for (; e + 12 < cnt; e += 16) {
        uint2 r0 = seg[e], r1 = seg[e + 4], r2 = seg[e + 8], r3 = seg[e + 12];
        unsigned int v0 = *(const unsigned int*)(t + (size_t)(r0.x & 0xFFFFu) * 128 + lane * 2);
        unsigned int v1 = *(const unsigned int*)(t + (size_t)(r1.x & 0xFFFFu) * 128 + lane * 2);
        unsigned int v2 = *(const unsigned int*)(t + (size_t)(r2.x & 0xFFFFu) * 128 + lane * 2);
        unsigned int v3 = *(const unsigned int*)(t + (size_t)(r3.x & 0xFFFFu) * 128 + lane * 2);
        float w0 = asfloat_u32(r0.y), w1 = asfloat_u32(r1.y);
        float w2 = asfloat_u32(r2.y), w3 = asfloat_u32(r3.y);
        int d0 = (r0.x >> 16) & 63, d1 = (r1.x >> 16) & 63;
        int d2 = (r2.x >> 16) & 63, d3 = (r3.x >> 16) & 63;
        atomicAdd(&acc[d0 * 128 + lane * 2],     w0 * asfloat_u32(v0 << 16));
        atomicAdd(&acc[d0 * 128 + lane * 2 + 1], w0 * asfloat_u32(v0 & 0xFFFF0000u));
        atomicAdd(&acc[d1 * 128 + lane * 2],     w1 * asfloat_u32(v1 << 16));
        atomicAdd(&acc[d1 * 128 + lane * 2 + 1], w1 * asfloat_u32(v1 & 0xFFFF0000u));
        atomicAdd(&acc[d2 * 128 + lane * 2],     w2 * asfloat_u32(v2 << 16));
        atomicAdd(&acc[d2 * 128 + lane * 2 + 1], w2 * asfloat_u32(v2 & 0xFFFF0000u));
        atomicAdd(&acc[d3 * 128 + lane * 2],     w3 * asfloat_u32(v3 << 16));
        atomicAdd(&acc[d3 * 128 + lane * 2 + 1], w3 * asfloat_u32(v3 & 0xFFFF0000u));
    }
    for (; e < cnt; e += 4) {
        uint2 r = seg[e];
        unsigned int v = *(const unsigned int*)(t + (size_t)(r.x & 0xFFFFu) * 128 + lane * 2);
        float w = asfloat_u32(r.y);
        int d = (r.x >> 16) & 63;
        atomicAdd(&acc[d * 128 + lane * 2],     w * asfloat_u32(v << 16));
        atomicAdd(&acc[d * 128 + lane * 2 + 1], w * asfloat_u32(v & 0xFFFF0000u));
    }
    __syncthreads();

    // epilogue: bias + relu, pack 2 bf16 per uint
    for (int p = tid; p < 64 * 64; p += 256) {
        int r = p >> 6;
        int f2 = (p & 63) * 2;
        int node = b * 64 + r;
        if (node < N_NODES) {
            float2 bb = *(const float2*)&bias[f2];
            float ax = fmaxf(acc[r * 128 + f2] + bb.x, 0.f);
            float ay = fmaxf(acc[r * 128 + f2 + 1] + bb.y, 0.f);
            unsigned int packed = ((unsigned int)f2bf(ax)) | (((unsigned int)f2bf(ay)) << 16);
            *(unsigned int*)(out + (size_t)node * 128 + f2) = packed;
        }
    }
}

// ---------------- SpMM feat=40 LDS accumulator + bias + log_softmax ----------------
__global__ __launch_bounds__(256) void spmm_lds_logsoftmax(const unsigned short* __restrict__ t,
                                                           const uint2* __restrict__ binned2,
                                                           const int* __restrict__ subCnt,
                                                           const float* __restrict__ bias,
                                                           float* __restrict__ out) {
    __shared__ float acc[64 * 40];  // 10 KB
    __shared__ float mrow[64], lrow[64];
    const int b = blockIdx.x;
    const int tid = threadIdx.x;
    const int wave = tid >> 6;
    const int lane = tid & 63;
    const int cnt = subCnt[b];
    const uint2* seg = binned2 + (size_t)b * SUBCAP;

    for (int i = tid; i < 64 * 40; i += 256) acc[i] = 0.f;
    __syncthreads();

    const bool act = lane < NCLASS;
    int e = wave;
    for (; e + 12 < cnt; e += 16) {
        uint2 r0 = seg[e], r1 = seg[e + 4], r2 = seg[e + 8], r3 = seg[e + 12];
        if (act) {
            float v0 = asfloat_u32((unsigned int)t[(size_t)(r0.x & 0xFFFFu) * NCLASS + lane] << 16);
            float v1 = asfloat_u32((unsigned int)t[(size_t)(r1.x & 0xFFFFu) * NCLASS + lane] << 16);
            float v2 = asfloat_u32((unsigned int)t[(size_t)(r2.x & 0xFFFFu) * NCLASS + lane] << 16);
            float v3 = asfloat_u32((unsigned int)t[(size_t)(r3.x & 0xFFFFu) * NCLASS + lane] << 16);
            atomicAdd(&acc[((r0.x >> 16) & 63) * 40 + lane], asfloat_u32(r0.y) * v0);
            atomicAdd(&acc[((r1.x >> 16) & 63) * 40 + lane], asfloat_u32(r1.y) * v1);
            atomicAdd(&acc[((r2.x >> 16) & 63) * 40 + lane], asfloat_u32(r2.y) * v2);
            atomicAdd(&acc[((r3.x >> 16) & 63) * 40 + lane], asfloat_u32(r3.y) * v3);
        }
    }
    for (; e < cnt; e += 4) {
        uint2 r = seg[e];
        if (act) {
            float v = asfloat_u32((unsigned int)t[(size_t)(r.x & 0xFFFFu) * NCLASS + lane] << 16);
            atomicAdd(&acc[((r.x >> 16) & 63) * 40 + lane], asfloat_u32(r.y) * v);
        }
    }
    __syncthreads();

    // per-row softmax stats (threads 0..63, serial over 40)
    if (tid < 64) {
        float m = -INFINITY;
#pragma unroll
        for (int j = 0; j < NCLASS; ++j) m = fmaxf(m, acc[tid * 40 + j] + bias[j]);
        float s = 0.f;
#pragma unroll
        for (int j = 0; j < NCLASS; ++j) s += __expf(acc[tid * 40 + j] + bias[j] - m);
        mrow[tid] = m;
        lrow[tid] = __logf(s);
    }
    __syncthreads();

    for (int p = tid; p < 64 * NCLASS; p += 256) {
        int r = p / NCLASS;
        int j = p - r * NCLASS;
        int node = b * 64 + r;
        if (node < N_NODES)
            out[(size_t)node * NCLASS + j] = acc[r * 40 + j] + bias[j] - mrow[r] - lrow[r];
    }
}

// ---------------- launch ----------------

extern "C" void kernel_launch(void* const* d_in, const int* in_sizes, int n_in,
                              void* d_out, int out_size, void* d_ws, size_t ws_size,
                              hipStream_t stream) {
    const float* x = (const float*)d_in[0];
    const int* edge_src = (const int*)d_in[1];
    const int* edge_dst = (const int*)d_in[2];
    const float* edge_weight = (const float*)d_in[3];
    const float* W1 = (const float*)d_in[4];
    const float* b1 = (const float*)d_in[5];
    const float* Wh = (const float*)d_in[6];
    const float* bh = (const float*)d_in[7];
    const float* W2 = (const float*)d_in[8];
    const float* b2 = (const float*)d_in[9];
    float* out = (float*)d_out;

    size_t off = 0;
    auto carve = [&](size_t bytes) {
        void* p = (char*)d_ws + off;
        off += (bytes + 511) & ~(size_t)511;
        return p;
    };
    unsigned short* tb = (unsigned short*)carve((size_t)N_NODES * 128 * 2);
    unsigned short* hb = (unsigned short*)carve((size_t)N_NODES * 128 * 2);
    unsigned short* t3 = (unsigned short*)carve((size_t)N_NODES * NCLASS * 2);
    unsigned short* Wt1 = (unsigned short*)carve((size_t)NFEAT * NHID * 2);
    unsigned short* Wth = (unsigned short*)carve((size_t)NHID * NHID * 2);
    int* bucketCursor = (int*)carve((size_t)NBUCKETS * 4);
    int* subCnt = (int*)carve((size_t)NSUB * 4);
    uint2* binned = (uint2*)carve((size_t)NBUCKETS * BUCKET_CAP * 8);
    uint2* binned2 = (uint2*)carve((size_t)NSUB * SUBCAP * 8);
    (void)ws_size; (void)n_in; (void)in_sizes; (void)out_size;

    const int prepBlocks = (NFEAT * NHID + NHID * NHID + NBUCKETS + 255) / 256;  // 321
    const int binBlocks = (N_EDGES + 4095) / 4096;   // 391
    const int tileBlocks = (N_NODES + 127) / 128;    // 391
    const int gemmBlocks = (N_NODES + 63) / 64;      // 782
    const int subBlocks = (N_NODES + 63) / 64;       // 782

    // prep + CSR-ish build
    prep_kernel<<<prepBlocks, 256, 0, stream>>>(W1, Wt1, Wh, Wth, bucketCursor);
    bin_kernel<<<binBlocks, 256, 0, stream>>>(edge_src, edge_dst, edge_weight,
                                              bucketCursor, binned, N_EDGES);
    sort_kernel<<<NBUCKETS, 256, 0, stream>>>(binned, bucketCursor, binned2, subCnt);

    // Layer 1
    gemm_tile_n128<false><<<tileBlocks, 256, 0, stream>>>(x, Wt1, tb, N_NODES, NFEAT);
    spmm_lds_relu<<<subBlocks, 256, 0, stream>>>(tb, binned2, subCnt, b1, hb);

    // Layer 2
    gemm_tile_n128<true><<<tileBlocks, 256, 0, stream>>>(hb, Wth, tb, N_NODES, NHID);
    spmm_lds_relu<<<subBlocks, 256, 0, stream>>>(tb, binned2, subCnt, bh, hb);

    // Layer 3
    gemm_n40_bf16A<<<gemmBlocks, 256, 0, stream>>>(hb, W2, t3, N_NODES);
    spmm_lds_logsoftmax<<<subBlocks, 256, 0, stream>>>(t3, binned2, subCnt, b2, out);
}

// Round 8
// 437.151 us; speedup vs baseline: 7.7541x; 7.7541x over previous
//
#include <hip/hip_runtime.h>
#include <hip/hip_bf16.h>
#include <math.h>

#define N_NODES 50000
#define N_EDGES 1600000
#define NFEAT 512
#define NHID 128
#define NCLASS 40

#define NBUCKETS 196      // ceil(N_NODES / 256), dst>>8
#define BUCKET_CAP 16384  // avg fill ~8163 -> huge margin

typedef __attribute__((ext_vector_type(8))) short bf16x8;
typedef __attribute__((ext_vector_type(4))) float f32x4;

static __device__ __forceinline__ float asfloat_u32(unsigned int u) {
    union { unsigned int u; float f; } c;
    c.u = u;
    return c.f;
}
static __device__ __forceinline__ unsigned int asu32_f(float f) {
    union { float f; unsigned int u; } c;
    c.f = f;
    return c.u;
}
static __device__ __forceinline__ unsigned short f2bf(float f) {
    union { float f; unsigned int u; } c;
    c.f = f;
    unsigned int r = c.u + 0x7FFFu + ((c.u >> 16) & 1u);  // RTN-even
    return (unsigned short)(r >> 16);
}

// ---------------- prep: bucket cursor init + both weight transposes ----------------
__global__ __launch_bounds__(256) void prep_kernel(const float* __restrict__ W1,
                                                   unsigned short* __restrict__ Wt1,
                                                   const float* __restrict__ Wh,
                                                   unsigned short* __restrict__ Wth,
                                                   int* __restrict__ bucketCursor) {
    int idx = blockIdx.x * 256 + threadIdx.x;
    if (idx < NFEAT * NHID) {  // Wt1[n][k] = bf16(W1[k][n])
        int k = idx >> 7;
        int n = idx & 127;
        Wt1[(size_t)n * NFEAT + k] = f2bf(W1[idx]);
    } else if (idx < NFEAT * NHID + NHID * NHID) {
        int j = idx - NFEAT * NHID;
        int k = j >> 7;
        int n = j & 127;
        Wth[(size_t)n * NHID + k] = f2bf(Wh[j]);
    } else {
        int j = idx - (NFEAT * NHID + NHID * NHID);
        if (j < NBUCKETS) bucketCursor[j] = j * BUCKET_CAP;
    }
}

// ---------------- GEMM (64-row tile) body, N=128 ----------------
// C[M x 128](bf16) = A[M x K] @ Wt^T ; Wt is [128][K] bf16.
// 256 thr / 4 waves; wave w covers rows [w*16, w*16+16); 8 col MFMA tiles.
// LDS rows padded to LDP=40 bf16 (80B stride, <=2-way bank aliasing = free).
#define LDP 40
#define GEMM_LDS_BYTES ((64 + 128) * LDP * 2)

template <bool A_IS_BF16>
static __device__ __forceinline__ void gemm64_body(const void* __restrict__ Ap,
                                                   const unsigned short* __restrict__ Wt,
                                                   unsigned short* __restrict__ C,
                                                   const int M, const int K,
                                                   char* smem, int bid) {
    unsigned short* As = (unsigned short*)smem;             // 64 x LDP
    unsigned short* Bs = (unsigned short*)smem + 64 * LDP;  // 128 x LDP
    const int tid = threadIdx.x;
    const int wave = tid >> 6;
    const int lane = tid & 63;
    const int ln = lane & 15;
    const int quad = lane >> 4;
    const int row0 = bid * 64;

    const int ar = tid >> 2;            // A staging row 0..63
    const int ac = (tid & 3) * 8;       // A staging k-offset
    const bool arOk = (row0 + ar) < M;
    const int bn = tid >> 1;            // B staging col(n) 0..127
    const int bk = (tid & 1) * 16;      // B staging k-offset (16 elems = 2x bf16x8)

    f32x4 acc[8];
#pragma unroll
    for (int t = 0; t < 8; ++t) acc[t] = (f32x4){0.f, 0.f, 0.f, 0.f};

    for (int kc = 0; kc < K; kc += 32) {
        bf16x8 va;
        if (A_IS_BF16) {
            if (arOk) {
                va = *(const bf16x8*)((const unsigned short*)Ap +
                                      (size_t)(row0 + ar) * K + kc + ac);
            } else {
#pragma unroll
                for (int i = 0; i < 8; ++i) va[i] = 0;
            }
        } else {
            if (arOk) {
                const float* Af = (const float*)Ap + (size_t)(row0 + ar) * K + kc + ac;
                float4 f0 = *(const float4*)(Af);
                float4 f1 = *(const float4*)(Af + 4);
                va[0] = (short)f2bf(f0.x); va[1] = (short)f2bf(f0.y);
                va[2] = (short)f2bf(f0.z); va[3] = (short)f2bf(f0.w);
                va[4] = (short)f2bf(f1.x); va[5] = (short)f2bf(f1.y);
                va[6] = (short)f2bf(f1.z); va[7] = (short)f2bf(f1.w);
            } else {
#pragma unroll
                for (int i = 0; i < 8; ++i) va[i] = 0;
            }
        }
        const unsigned short* Bg = Wt + (size_t)bn * K + kc + bk;
        bf16x8 vb0 = *(const bf16x8*)Bg;
        bf16x8 vb1 = *(const bf16x8*)(Bg + 8);

        __syncthreads();  // previous iteration's compute done
        *(bf16x8*)&As[ar * LDP + ac] = va;
        *(bf16x8*)&Bs[bn * LDP + bk] = vb0;
        *(bf16x8*)&Bs[bn * LDP + bk + 8] = vb1;
        __syncthreads();

        bf16x8 a = *(const bf16x8*)&As[(wave * 16 + ln) * LDP + quad * 8];
#pragma unroll
        for (int t = 0; t < 8; ++t) {
            bf16x8 b = *(const bf16x8*)&Bs[(t * 16 + ln) * LDP + quad * 8];
            acc[t] = __builtin_amdgcn_mfma_f32_16x16x32_bf16(a, b, acc[t], 0, 0, 0);
        }
    }

#pragma unroll
    for (int t = 0; t < 8; ++t) {
#pragma unroll
        for (int r = 0; r < 4; ++r) {
            int row = row0 + wave * 16 + quad * 4 + r;
            if (row < M) C[(size_t)row * 128 + t * 16 + ln] = f2bf(acc[t][r]);
        }
    }
}

// ---------------- bin body: bucket edges by dst>>8 ----------------
// Record: x = src | (dstLow8)<<16 ; y = fp32 weight bits.
static __device__ __forceinline__ void bin_body(const int* __restrict__ src,
                                                const int* __restrict__ dst,
                                                const float* __restrict__ w,
                                                int* __restrict__ bucketCursor,
                                                uint2* __restrict__ binned,
                                                int n, char* smem, int bid) {
    int* hist = (int*)smem;            // NBUCKETS
    int* cur = (int*)smem + NBUCKETS;  // NBUCKETS
    const int tid = threadIdx.x;
    const int base = bid * 4096;
    if (tid < NBUCKETS) hist[tid] = 0;
    __syncthreads();
#pragma unroll
    for (int r = 0; r < 16; ++r) {
        int e = base + r * 256 + tid;
        if (e < n) atomicAdd(&hist[dst[e] >> 8], 1);
    }
    __syncthreads();
    if (tid < NBUCKETS && hist[tid] > 0)
        cur[tid] = atomicAdd(&bucketCursor[tid], hist[tid]);
    __syncthreads();
#pragma unroll
    for (int r = 0; r < 16; ++r) {
        int e = base + r * 256 + tid;
        if (e < n) {
            int d = dst[e];
            int pos = atomicAdd(&cur[d >> 8], 1);
            uint2 rec;
            rec.x = (unsigned int)src[e] | ((unsigned int)(d & 255) << 16);
            rec.y = asu32_f(w[e]);
            binned[pos] = rec;
        }
    }
}

// ---------------- fused: GEMM1 (782 blocks) || bin (391 blocks) ----------------
#define GEMM1_BLOCKS 782
#define BIN_BLOCKS 391
__global__ __launch_bounds__(256) void fused_gemm1_bin(const float* __restrict__ x,
                                                       const unsigned short* __restrict__ Wt1,
                                                       unsigned short* __restrict__ tb,
                                                       const int* __restrict__ src,
                                                       const int* __restrict__ dst,
                                                       const float* __restrict__ w,
                                                       int* __restrict__ bucketCursor,
                                                       uint2* __restrict__ binned) {
    __shared__ char smem[GEMM_LDS_BYTES];
    if (blockIdx.x < GEMM1_BLOCKS) {
        gemm64_body<false>(x, Wt1, tb, N_NODES, NFEAT, smem, blockIdx.x);
    } else {
        bin_body(src, dst, w, bucketCursor, binned, N_EDGES, smem,
                 blockIdx.x - GEMM1_BLOCKS);
    }
}

// ---------------- standalone GEMM layer 2 ----------------
__global__ __launch_bounds__(256) void gemm64_l2(const unsigned short* __restrict__ A,
                                                 const unsigned short* __restrict__ Wt,
                                                 unsigned short* __restrict__ C) {
    __shared__ char smem[GEMM_LDS_BYTES];
    gemm64_body<true>(A, Wt, C, N_NODES, NHID, smem, blockIdx.x);
}

// ---------------- build_csr (inline bucket scan): 4B edge records ----------------
// pairs[pos] = src(16b) | bf16(weight)(16b high)
__global__ __launch_bounds__(256) void build_csr(const uint2* __restrict__ binned,
                                                 const int* __restrict__ bucketCursor,
                                                 unsigned int* __restrict__ pairs,
                                                 int* __restrict__ row_ptr) {
    __shared__ int bs[256];
    __shared__ int hist[256];
    __shared__ int sc[256];
    __shared__ int cur[256];
    const int b = blockIdx.x;
    const int tid = threadIdx.x;

    // inline exclusive scan of bucket fills
    int c = (tid < NBUCKETS) ? (bucketCursor[tid] - tid * BUCKET_CAP) : 0;
    bs[tid] = c;
    __syncthreads();
    for (int off = 1; off < 256; off <<= 1) {
        int t = (tid >= off) ? bs[tid - off] : 0;
        __syncthreads();
        bs[tid] += t;
        __syncthreads();
    }
    const int cnt = bucketCursor[b] - b * BUCKET_CAP;
    const int segStart = bs[b] - cnt;  // exclusive prefix at b
    if (b == NBUCKETS - 1 && tid == 0) row_ptr[N_NODES] = bs[NBUCKETS - 1];
    const uint2* seg = binned + (size_t)b * BUCKET_CAP;

    hist[tid] = 0;
    __syncthreads();
    for (int i = tid; i < cnt; i += 256)
        atomicAdd(&hist[seg[i].x >> 16], 1);
    __syncthreads();
    int v = hist[tid];
    sc[tid] = v;
    __syncthreads();
    for (int off = 1; off < 256; off <<= 1) {
        int t = (tid >= off) ? sc[tid - off] : 0;
        __syncthreads();
        sc[tid] += t;
        __syncthreads();
    }
    int excl = sc[tid] - v;
    int node = b * 256 + tid;
    if (node < N_NODES) row_ptr[node] = segStart + excl;
    cur[tid] = segStart + excl;
    __syncthreads();
    for (int i = tid; i < cnt; i += 256) {
        uint2 p = seg[i];
        int pos = atomicAdd(&cur[p.x >> 16], 1);
        pairs[pos] = (p.x & 0xFFFFu) | ((unsigned int)f2bf(asfloat_u32(p.y)) << 16);
    }
}

// ---------------- GEMM, N=40, K=128, A bf16 -> C bf16 ----------------
__global__ __launch_bounds__(256) void gemm_n40_bf16A(const unsigned short* __restrict__ A,
                                                      const float* __restrict__ Bm,
                                                      unsigned short* __restrict__ C, int M) {
    __shared__ float As[64][132];
    __shared__ float Bs[128 * 40];
    const int tid = threadIdx.x;
    const int tr = tid >> 2;
    const int tc = tid & 3;
    const int row0 = blockIdx.x * 64;

#pragma unroll
    for (int q = tid; q < 2048; q += 256) {
        int r = q >> 5;
        int c = (q & 31) << 2;
        int row = row0 + r;
        uint2 u = make_uint2(0u, 0u);
        if (row < M) u = *(const uint2*)(A + (size_t)row * 128 + c);
        As[r][c + 0] = asfloat_u32(u.x << 16);
        As[r][c + 1] = asfloat_u32(u.x & 0xFFFF0000u);
        As[r][c + 2] = asfloat_u32(u.y << 16);
        As[r][c + 3] = asfloat_u32(u.y & 0xFFFF0000u);
    }
    for (int q = tid; q < 128 * 40; q += 256) Bs[q] = Bm[q];
    __syncthreads();

    float acc[10];
#pragma unroll
    for (int j = 0; j < 10; ++j) acc[j] = 0.f;

    for (int k = 0; k < 128; ++k) {
        float a = As[tr][k];
#pragma unroll
        for (int j = 0; j < 10; ++j) acc[j] += a * Bs[k * 40 + tc * 10 + j];
    }

    int row = row0 + tr;
    if (row < M) {
#pragma unroll
        for (int j = 0; j < 10; ++j) C[(size_t)row * 40 + tc * 10 + j] = f2bf(acc[j]);
    }
}

// ---------------- SpMM (CSR gather, bf16 rows) + bias + ReLU, feat=128 ----------------
// one wave per dst node; 4B edge records: src = p & 0xFFFF, weight = bits(p & 0xFFFF0000)
__global__ __launch_bounds__(256) void spmm_bias_relu_bf16(const unsigned short* __restrict__ t,
                                                           const int* __restrict__ row_ptr,
                                                           const unsigned int* __restrict__ pairs,
                                                           const float* __restrict__ bias,
                                                           unsigned short* __restrict__ out) {
    const int node = blockIdx.x * 4 + (threadIdx.x >> 6);
    const int lane = threadIdx.x & 63;
    const int e0 = row_ptr[node];
    const int e1 = row_ptr[node + 1];
    float ax = 0.f, ay = 0.f;
    int e = e0;
    for (; e + 8 <= e1; e += 8) {
        unsigned int p0 = pairs[e],     p1 = pairs[e + 1], p2 = pairs[e + 2], p3 = pairs[e + 3];
        unsigned int p4 = pairs[e + 4], p5 = pairs[e + 5], p6 = pairs[e + 6], p7 = pairs[e + 7];
        unsigned int v0 = *(const unsigned int*)(t + (size_t)(p0 & 0xFFFFu) * 128 + lane * 2);
        unsigned int v1 = *(const unsigned int*)(t + (size_t)(p1 & 0xFFFFu) * 128 + lane * 2);
        unsigned int v2 = *(const unsigned int*)(t + (size_t)(p2 & 0xFFFFu) * 128 + lane * 2);
        unsigned int v3 = *(const unsigned int*)(t + (size_t)(p3 & 0xFFFFu) * 128 + lane * 2);
        unsigned int v4 = *(const unsigned int*)(t + (size_t)(p4 & 0xFFFFu) * 128 + lane * 2);
        unsigned int v5 = *(const unsigned int*)(t + (size_t)(p5 & 0xFFFFu) * 128 + lane * 2);
        unsigned int v6 = *(const unsigned int*)(t + (size_t)(p6 & 0xFFFFu) * 128 + lane * 2);
        unsigned int v7 = *(const unsigned int*)(t + (size_t)(p7 & 0xFFFFu) * 128 + lane * 2);
        float w0 = asfloat_u32(p0 & 0xFFFF0000u), w1 = asfloat_u32(p1 & 0xFFFF0000u);
        float w2 = asfloat_u32(p2 & 0xFFFF0000u), w3 = asfloat_u32(p3 & 0xFFFF0000u);
        float w4 = asfloat_u32(p4 & 0xFFFF0000u), w5 = asfloat_u32(p5 & 0xFFFF0000u);
        float w6 = asfloat_u32(p6 & 0xFFFF0000u), w7 = asfloat_u32(p7 & 0xFFFF0000u);
        ax += w0 * asfloat_u32(v0 << 16); ay += w0 * asfloat_u32(v0 & 0xFFFF0000u);
        ax += w1 * asfloat_u32(v1 << 16); ay += w1 * asfloat_u32(v1 & 0xFFFF0000u);
        ax += w2 * asfloat_u32(v2 << 16); ay += w2 * asfloat_u32(v2 & 0xFFFF0000u);
        ax += w3 * asfloat_u32(v3 << 16); ay += w3 * asfloat_u32(v3 & 0xFFFF0000u);
        ax += w4 * asfloat_u32(v4 << 16); ay += w4 * asfloat_u32(v4 & 0xFFFF0000u);
        ax += w5 * asfloat_u32(v5 << 16); ay += w5 * asfloat_u32(v5 & 0xFFFF0000u);
        ax += w6 * asfloat_u32(v6 << 16); ay += w6 * asfloat_u32(v6 & 0xFFFF0000u);
        ax += w7 * asfloat_u32(v7 << 16); ay += w7 * asfloat_u32(v7 & 0xFFFF0000u);
    }
    for (; e < e1; ++e) {
        unsigned int p = pairs[e];
        float w = asfloat_u32(p & 0xFFFF0000u);
        unsigned int v = *(const unsigned int*)(t + (size_t)(p & 0xFFFFu) * 128 + lane * 2);
        ax += w * asfloat_u32(v << 16);
        ay += w * asfloat_u32(v & 0xFFFF0000u);
    }
    float2 b = *(const float2*)&bias[lane * 2];
    ax = fmaxf(ax + b.x, 0.f);
    ay = fmaxf(ay + b.y, 0.f);
    unsigned int packed = ((unsigned int)f2bf(ax)) | (((unsigned int)f2bf(ay)) << 16);
    *(unsigned int*)(out + (size_t)node * 128 + lane * 2) = packed;
}

// ---------------- SpMM feat=40 (bf16 rows) + bias + log_softmax ----------------
__global__ __launch_bounds__(256) void spmm_logsoftmax(const unsigned short* __restrict__ t,
                                                       const int* __restrict__ row_ptr,
                                                       const unsigned int* __restrict__ pairs,
                                                       const float* __restrict__ bias,
                                                       float* __restrict__ out) {
    const int node = blockIdx.x * 4 + (threadIdx.x >> 6);
    const int lane = threadIdx.x & 63;
    const int e0 = row_ptr[node];
    const int e1 = row_ptr[node + 1];
    const bool act = lane < NCLASS;
    float acc = 0.f;
    int e = e0;
    for (; e + 4 <= e1; e += 4) {
        unsigned int p0 = pairs[e], p1 = pairs[e + 1], p2 = pairs[e + 2], p3 = pairs[e + 3];
        if (act) {
            float v0 = asfloat_u32((unsigned int)t[(size_t)(p0 & 0xFFFFu) * NCLASS + lane] << 16);
            float v1 = asfloat_u32((unsigned int)t[(size_t)(p1 & 0xFFFFu) * NCLASS + lane] << 16);
            float v2 = asfloat_u32((unsigned int)t[(size_t)(p2 & 0xFFFFu) * NCLASS + lane] << 16);
            float v3 = asfloat_u32((unsigned int)t[(size_t)(p3 & 0xFFFFu) * NCLASS + lane] << 16);
            acc += asfloat_u32(p0 & 0xFFFF0000u) * v0 + asfloat_u32(p1 & 0xFFFF0000u) * v1 +
                   asfloat_u32(p2 & 0xFFFF0000u) * v2 + asfloat_u32(p3 & 0xFFFF0000u) * v3;
        }
    }
    for (; e < e1; ++e) {
        unsigned int p = pairs[e];
        if (act)
            acc += asfloat_u32(p & 0xFFFF0000u) *
                   asfloat_u32((unsigned int)t[(size_t)(p & 0xFFFFu) * NCLASS + lane] << 16);
    }
    float logit = act ? (acc + bias[lane]) : -INFINITY;
    float m = logit;
#pragma unroll
    for (int off = 32; off; off >>= 1) m = fmaxf(m, __shfl_xor(m, off));
    float ex = act ? __expf(logit - m) : 0.f;
    float ssum = ex;
#pragma unroll
    for (int off = 32; off; off >>= 1) ssum += __shfl_xor(ssum, off);
    if (act) out[(size_t)node * NCLASS + lane] = logit - m - __logf(ssum);
}

// ---------------- launch ----------------

extern "C" void kernel_launch(void* const* d_in, const int* in_sizes, int n_in,
                              void* d_out, int out_size, void* d_ws, size_t ws_size,
                              hipStream_t stream) {
    const float* x = (const float*)d_in[0];
    const int* edge_src = (const int*)d_in[1];
    const int* edge_dst = (const int*)d_in[2];
    const float* edge_weight = (const float*)d_in[3];
    const float* W1 = (const float*)d_in[4];
    const float* b1 = (const float*)d_in[5];
    const float* Wh = (const float*)d_in[6];
    const float* bh = (const float*)d_in[7];
    const float* W2 = (const float*)d_in[8];
    const float* b2 = (const float*)d_in[9];
    float* out = (float*)d_out;

    size_t off = 0;
    auto carve = [&](size_t bytes) {
        void* p = (char*)d_ws + off;
        off += (bytes + 511) & ~(size_t)511;
        return p;
    };
    unsigned short* tb = (unsigned short*)carve((size_t)N_NODES * 128 * 2);
    unsigned short* hb = (unsigned short*)carve((size_t)N_NODES * 128 * 2);
    unsigned short* t3 = (unsigned short*)carve((size_t)N_NODES * NCLASS * 2);
    unsigned short* Wt1 = (unsigned short*)carve((size_t)NFEAT * NHID * 2);
    unsigned short* Wth = (unsigned short*)carve((size_t)NHID * NHID * 2);
    int* row_ptr = (int*)carve((size_t)(N_NODES + 4) * 4);
    int* bucketCursor = (int*)carve((size_t)NBUCKETS * 4);
    uint2* binned = (uint2*)carve((size_t)NBUCKETS * BUCKET_CAP * 8);
    unsigned int* pairs = (unsigned int*)carve((size_t)N_EDGES * 4);
    (void)ws_size; (void)n_in; (void)in_sizes; (void)out_size;

    const int prepBlocks = (NFEAT * NHID + NHID * NHID + NBUCKETS + 255) / 256;  // 321
    const int spmmBlocks = N_NODES / 4;            // 12500
    const int gemmBlocks = (N_NODES + 63) / 64;    // 782

    // prep (weights + cursors)
    prep_kernel<<<prepBlocks, 256, 0, stream>>>(W1, Wt1, Wh, Wth, bucketCursor);

    // GEMM1 || bin (independent work fused into one launch)
    fused_gemm1_bin<<<GEMM1_BLOCKS + BIN_BLOCKS, 256, 0, stream>>>(
        x, Wt1, tb, edge_src, edge_dst, edge_weight, bucketCursor, binned);

    // CSR finalize (inline bucket scan)
    build_csr<<<NBUCKETS, 256, 0, stream>>>(binned, bucketCursor, pairs, row_ptr);

    // Layer 1 aggregate
    spmm_bias_relu_bf16<<<spmmBlocks, 256, 0, stream>>>(tb, row_ptr, pairs, b1, hb);

    // Layer 2
    gemm64_l2<<<gemmBlocks, 256, 0, stream>>>(hb, Wth, tb);
    spmm_bias_relu_bf16<<<spmmBlocks, 256, 0, stream>>>(tb, row_ptr, pairs, bh, hb);

    // Layer 3
    gemm_n40_bf16A<<<gemmBlocks, 256, 0, stream>>>(hb, W2, t3, N_NODES);
    spmm_logsoftmax<<<spmmBlocks, 256, 0, stream>>>(t3, row_ptr, pairs, b2, out);
}